// Round 5
// baseline (321.681 us; speedup 1.0000x reference)
//
#include <hip/hip_runtime.h>

#define CI 64
#define CO 128
#define HH 64
#define WW 64
#define OH 62
#define OW 62

typedef __attribute__((ext_vector_type(8))) short short8x;
typedef __attribute__((ext_vector_type(16))) float f32x16;

// Weight scratch as a module device-global: NOT d_ws, so the harness's timed
// 0xAA ws re-poison never touches it. wprep rewrites it every launch.
__device__ ushort g_wt[9 * CO * CI];   // [tap][co][ci] bf16

__device__ __forceinline__ ushort bf16rne(float f) {
    unsigned u = __builtin_bit_cast(unsigned, f);
    u += 0x7fffu + ((u >> 16) & 1u);
    return (ushort)(u >> 16);
}

__global__ __launch_bounds__(256)
void wprep(const float* __restrict__ w) {
    const int idx = blockIdx.x * 256 + threadIdx.x;   // 73728 total
    const int kk = idx >> 13;
    const int rem = idx & 8191;
    const int co = rem >> 6, ci = rem & 63;
    g_wt[idx] = bf16rne(w[(co * 64 + ci) * 9 + kk]);
}

// Block = (batch, 8-output-row group), 512 threads = 8 waves.
// Wave (hq = co quarter, rw = row): 32 co x 64 px, acc[2] over px halves ->
// each A frag (global, L2-hot g_wt) feeds 2 MFMAs; B from swizzled LDS ring.
// Rolling 4-row LDS ring, 4 tiles of 2 output rows; prefetch next 2 input rows
// into registers before each tile's K-loop (MFMA hides the HBM latency).
__global__ __launch_bounds__(512, 4)
void conv_fused(const float* __restrict__ x, const float* __restrict__ bias,
                float* __restrict__ out) {
    __shared__ ushort Xl[264 * 64];   // 4 ring slots x 66 px x 64 ci (33.8 KB)
    __shared__ float  sB[CO];

    const int tid = threadIdx.x;
    const int wv = tid >> 6, L = tid & 63, l31 = L & 31, q = L >> 5;
    const int hq = wv >> 1;          // co quarter: co base = hq*32
    const int rw = wv & 1;           // output row (0/1) within tile
    const int b = blockIdx.y, base = blockIdx.x * 8;

    if (tid < CO) sB[tid] = bias[tid];

    const float* xb = x + (size_t)b * CI * HH * WW;

    // ---- prologue: stage input rows base..base+3 into ring slots 0..3 ----
    for (int i = tid; i < 528; i += 512) {
        const int pxi = i >> 1, half = i & 1;
        const int r = pxi / 66, cpos = pxi - r * 66;
        const bool valid = cpos < 64;                 // cols 64,65 zero-filled
        const float* xcol = xb + (size_t)(base + r) * WW + cpos;
        ushort* dst = &Xl[pxi * 64];
        const int pm = pxi & 7;
        #pragma unroll
        for (int cc = 0; cc < 4; ++cc) {
            const int c = half * 4 + cc;
            ushort tmp[8];
            #pragma unroll
            for (int j = 0; j < 8; ++j) {
                float v = valid ? xcol[(c * 8 + j) * (HH * WW)] : 0.f;
                tmp[j] = bf16rne(v);
            }
            *(uint4*)(dst + ((c ^ pm) * 8)) = *(const uint4*)tmp;
        }
    }

    // A frag base (verified layout): lane holds A[m=l31][k=q*8+j], co = hq*32+l31
    const ushort* wbase = g_wt + (hq * 32 + l31) * 64 + q * 8;

    f32x16 acc[2];
    #pragma unroll
    for (int nt = 0; nt < 2; ++nt)
        #pragma unroll
        for (int r = 0; r < 16; ++r) acc[nt][r] = 0.f;

    // per-iter prefetch role: fully coalesced (lane -> col), 16 floats/thread
    const int pcol = tid & 63, prn = (tid >> 6) & 1, pcq = (tid >> 7) & 3;

    __syncthreads();

    for (int t = 0; t < 4; ++t) {
        if (base + 2 * t >= OH) break;
        const bool pf = (t < 3) && (base + 2 * t + 2 < OH);

        // ---- issue next-tile global loads BEFORE compute ----
        float pv[2][8];
        if (pf) {
            const float* xc = xb + (size_t)(base + 2 * t + 4 + prn) * WW + pcol;
            #pragma unroll
            for (int c = 0; c < 2; ++c)
                #pragma unroll
                for (int j = 0; j < 8; ++j)
                    pv[c][j] = xc[((pcq * 2 + c) * 8 + j) * (HH * WW)];
        }

        // ---- K-loop over 9 taps: A from L2 g_wt, B from LDS ring ----
        #pragma unroll
        for (int kk = 0; kk < 9; ++kk) {
            const int kr = kk / 3, kc = kk - kr * 3;
            const int slot = (2 * t + rw + kr) & 3;
            const int pxB0 = slot * 66 + kc + l31;     // nt=1 at +32 px: same swizzle f
            const ushort* bb = Xl + pxB0 * 64;
            const int f = pxB0 & 7;
            const ushort* wt_tap = wbase + kk * (CO * CI);
            #pragma unroll
            for (int s = 0; s < 4; ++s) {
                short8x a  = *(const short8x*)(wt_tap + s * 16);
                const int ob = (((s * 2 + q) ^ f) * 8);
                short8x b0 = *(const short8x*)(bb + ob);
                short8x b1 = *(const short8x*)(bb + 32 * 64 + ob);
                acc[0] = __builtin_amdgcn_mfma_f32_32x32x16_bf16(a, b0, acc[0], 0, 0, 0);
                acc[1] = __builtin_amdgcn_mfma_f32_32x32x16_bf16(a, b1, acc[1], 0, 0, 0);
            }
        }

        // ---- epilogue for this tile ----
        {
            const int oh = base + 2 * t + rw;
            #pragma unroll
            for (int nt = 0; nt < 2; ++nt) {
                const int col = nt * 32 + l31;
                if (col < OW) {
                    #pragma unroll
                    for (int reg = 0; reg < 16; ++reg) {
                        const int co = hq * 32 + 4 * q + (reg & 3) + 8 * (reg >> 2);
                        out[(((size_t)b * CO + co) * OH + oh) * OW + col] = acc[nt][reg] + sB[co];
                    }
                }
                #pragma unroll
                for (int r = 0; r < 16; ++r) acc[nt][r] = 0.f;
            }
        }

        // ---- commit prefetched rows into the ring ----
        if (pf) {
            __syncthreads();   // all waves done reading slots being replaced
            const int slotn = (2 * t + prn) & 3;       // rows 2t+4, 2t+5
            const int pxn = slotn * 66 + pcol;
            const int pmn = pxn & 7;
            ushort* dst = &Xl[pxn * 64];
            #pragma unroll
            for (int c = 0; c < 2; ++c) {
                ushort tmp[8];
                #pragma unroll
                for (int j = 0; j < 8; ++j) tmp[j] = bf16rne(pv[c][j]);
                *(uint4*)(dst + (((pcq * 2 + c) ^ pmn) * 8)) = *(const uint4*)tmp;
            }
            if (tid < 32) {    // zero-pad cols 64,65 of the two new rows
                const int zr = (tid >> 4) & 1, zc = 64 + ((tid >> 3) & 1), zch = tid & 7;
                const int pxz = ((2 * t + zr) & 3) * 66 + zc;
                const uint4 zz = {0u, 0u, 0u, 0u};
                *(uint4*)(&Xl[pxz * 64 + ((zch ^ (pxz & 7)) * 8)]) = zz;
            }
            __syncthreads();
        }
    }
}

extern "C" void kernel_launch(void* const* d_in, const int* in_sizes, int n_in,
                              void* d_out, int out_size, void* d_ws, size_t ws_size,
                              hipStream_t stream) {
    const float* x    = (const float*)d_in[0];
    const float* wgt  = (const float*)d_in[1];
    const float* bias = (const float*)d_in[2];
    float* out = (float*)d_out;

    wprep<<<dim3(288), 256, 0, stream>>>(wgt);
    conv_fused<<<dim3(8, 64), 512, 0, stream>>>(x, bias, out);
}

// Round 6
// 251.463 us; speedup vs baseline: 1.2792x; 1.2792x over previous
//
#include <hip/hip_runtime.h>

#define CI 64
#define CO 128
#define HH 64
#define WW 64
#define OH 62
#define OW 62

typedef __attribute__((ext_vector_type(8))) short short8x;
typedef __attribute__((ext_vector_type(16))) float f32x16;

// Weight scratch in a module device-global (not d_ws); wprep rewrites it every
// launch (idempotent). ~3 us, L2-resident for the main kernel.
__device__ ushort g_wt[9 * CO * CI];   // [tap][co][ci] bf16

__device__ __forceinline__ ushort bf16rne(float f) {
    unsigned u = __builtin_bit_cast(unsigned, f);
    u += 0x7fffu + ((u >> 16) & 1u);
    return (ushort)(u >> 16);
}

__global__ __launch_bounds__(256)
void wprep(const float* __restrict__ w) {
    const int idx = blockIdx.x * 256 + threadIdx.x;   // 73728 total
    const int kk = idx >> 13;
    const int rem = idx & 8191;
    const int co = rem >> 6, ci = rem & 63;
    g_wt[idx] = bf16rne(w[(co * 64 + ci) * 9 + kk]);
}

// Round-3 topology (grid 31x64, 2 output rows/block, one terminal epilogue ->
// proven FETCH 70 MB / WRITE 139 MB) with staging latency fixes:
//  - each staging thread issues ALL 64 ci loads before converting (1 vmcnt
//    drain instead of 8 serialized round-trips)
//  - tap-0 A-fragments prefetched before staging (latency hidden under drain)
// Wave (h = co-half, rw = row): A regs reused 2x, B b128 reused 2x -> 1:2.
__global__ __launch_bounds__(256, 2)
void conv_fused(const float* __restrict__ x, const float* __restrict__ bias,
                float* __restrict__ out) {
    __shared__ ushort Xl[264 * 64];   // 4 input rows x 66 px, 64 ci (33.8 KB)
    __shared__ float  sB[CO];

    const int tid = threadIdx.x;
    const int wv = tid >> 6, L = tid & 63, l31 = L & 31, q = L >> 5;
    const int h = wv >> 1;           // co half: co base = h*64
    const int rw = wv & 1;           // output row (0/1)
    const int b = blockIdx.y, oh0 = blockIdx.x * 2;

    if (tid < CO) sB[tid] = bias[tid];

    // ---- issue tap-0 A-fragment loads FIRST (verified layout: lane m=l31, k=q*8+j) ----
    const ushort* wbase = g_wt + (h * 64 + l31) * 64 + q * 8;
    short8x wbuf[2][8];   // [dbuf][m*4+s]
    #pragma unroll
    for (int m = 0; m < 2; ++m)
        #pragma unroll
        for (int s = 0; s < 4; ++s)
            wbuf[0][m * 4 + s] = *(const short8x*)(wbase + m * 2048 + s * 16);

    // ---- stage X: batch all 64 ci loads per px, then cvt+swizzled b128 writes ----
    const float* xb = x + (size_t)b * CI * HH * WW;
    #pragma unroll
    for (int g = 0; g < 2; ++g) {
        const int pxi = tid + g * 256;
        if (g == 0 || tid < 8) {                      // px 0..255, then 256..263
            const int r = pxi / 66, cpos = pxi - r * 66;
            const bool valid = cpos < 64;             // cols 64,65 zero-filled
            const float* xcol = xb + (size_t)(oh0 + r) * WW + cpos;
            float vv[64];
            #pragma unroll
            for (int j = 0; j < 64; ++j)
                vv[j] = valid ? xcol[j * (HH * WW)] : 0.f;
            ushort* dst = &Xl[pxi * 64];
            const int pm = pxi & 7;
            #pragma unroll
            for (int c = 0; c < 8; ++c) {
                ushort tmp[8];
                #pragma unroll
                for (int j = 0; j < 8; ++j) tmp[j] = bf16rne(vv[c * 8 + j]);
                *(uint4*)(dst + ((c ^ pm) * 8)) = *(const uint4*)tmp;
            }
        }
    }

    f32x16 acc[2][2];
    #pragma unroll
    for (int i = 0; i < 2; ++i)
        #pragma unroll
        for (int j = 0; j < 2; ++j)
            #pragma unroll
            for (int r = 0; r < 16; ++r) acc[i][j][r] = 0.f;

    __syncthreads();   // the only barrier

    // ---- K-loop: 9 taps, A double-buffered in regs, B from swizzled LDS ----
    #pragma unroll
    for (int kk = 0; kk < 9; ++kk) {
        const short8x* wf = wbuf[kk & 1];
        if (kk < 8) {   // prefetch next tap while this tap computes
            const ushort* nb = wbase + (kk + 1) * (CO * CI);
            #pragma unroll
            for (int m = 0; m < 2; ++m)
                #pragma unroll
                for (int s = 0; s < 4; ++s)
                    wbuf[(kk + 1) & 1][m * 4 + s] = *(const short8x*)(nb + m * 2048 + s * 16);
        }
        const int kr = kk / 3, kc = kk - kr * 3;
        const int pB = (rw + kr) * 66 + kc + l31;
        const ushort* bP0 = Xl + pB * 64;
        const int f0 = pB & 7;                        // (pB+32)&7 == f0
        #pragma unroll
        for (int s = 0; s < 4; ++s) {
            const int ob = (((s * 2 + q) ^ f0) * 8);
            short8x b0 = *(const short8x*)(bP0 + ob);
            short8x b1 = *(const short8x*)(bP0 + 32 * 64 + ob);
            acc[0][0] = __builtin_amdgcn_mfma_f32_32x32x16_bf16(wf[s],     b0, acc[0][0], 0, 0, 0);
            acc[0][1] = __builtin_amdgcn_mfma_f32_32x32x16_bf16(wf[s],     b1, acc[0][1], 0, 0, 0);
            acc[1][0] = __builtin_amdgcn_mfma_f32_32x32x16_bf16(wf[4 + s], b0, acc[1][0], 0, 0, 0);
            acc[1][1] = __builtin_amdgcn_mfma_f32_32x32x16_bf16(wf[4 + s], b1, acc[1][1], 0, 0, 0);
        }
    }

    // ---- terminal epilogue (all stores at once -> L2 merges partial lines) ----
    const int oh = oh0 + rw;
    #pragma unroll
    for (int mt = 0; mt < 2; ++mt)
        #pragma unroll
        for (int nt = 0; nt < 2; ++nt) {
            const int col = nt * 32 + l31;
            if (col < OW) {
                #pragma unroll
                for (int reg = 0; reg < 16; ++reg) {
                    const int co = h * 64 + mt * 32 + 4 * q + (reg & 3) + 8 * (reg >> 2);
                    out[(((size_t)b * CO + co) * OH + oh) * OW + col] = acc[mt][nt][reg] + sB[co];
                }
            }
        }
}

extern "C" void kernel_launch(void* const* d_in, const int* in_sizes, int n_in,
                              void* d_out, int out_size, void* d_ws, size_t ws_size,
                              hipStream_t stream) {
    const float* x    = (const float*)d_in[0];
    const float* wgt  = (const float*)d_in[1];
    const float* bias = (const float*)d_in[2];
    float* out = (float*)d_out;

    wprep<<<dim3(288), 256, 0, stream>>>(wgt);
    conv_fused<<<dim3(31, 64), 256, 0, stream>>>(x, bias, out);
}